// Round 10
// baseline (143.060 us; speedup 1.0000x reference)
//
#include <hip/hip_runtime.h>
#include <math.h>

// Chamfer distance, B=8, N=M=8192, D=3, fp32.
// out = mean_m( min_n dist2 ) + mean_n( min_m dist2 )
//
// dist2 = |q|^2 + (|t|^2 - 2 q.t); block stages its chunk's target quads
// (-2t, |t|^2) into LDS; inner loop = uniform-address ds_read_b128 broadcast.
// R9: Q=16 queries/thread. R8 post-mortem: VALU (48us/SIMD) and LDS return
// bandwidth (41us/CU) were nearly co-saturated; compiler refuses to hold a
// ping-pong batch live (VGPR=36 proved collapse), so overlap was fragile.
// Fix: halve LDS traffic per pair -- 16 queries amortize each quad read,
// LDS drops to ~20us/CU (43% load) under the 48us VALU floor.
// 4 waves/SIMD at ~105 VGPR; grid 1024 blocks = 4 blocks/CU, exactly resident.
// No atomics in minpass (R2 lesson); partial mins via coalesced stores.

#define B_      8
#define N_      8192
#define Q_      16           // queries per thread
#define S_      32           // target splits per pass
#define CHUNK_  (N_ / S_)    // 256 targets per block

__global__ __launch_bounds__(256)
void minpass_kernel(const float* __restrict__ x, const float* __restrict__ y,
                    float* __restrict__ partX, float* __restrict__ partY) {
    __shared__ float4 sq[CHUNK_ + 8];   // +8: ping-pong prefetch overshoot pad

    const int b    = blockIdx.y;
    const int z    = blockIdx.z;       // 0..63
    const int pass = z >> 5;           // 0: q=x,t=y   1: q=y,t=x
    const int s    = z & (S_ - 1);

    const float* qpts = pass ? y : x;
    const float* tpts = pass ? x : y;
    float*       part = pass ? partY : partX;

    // ---- stage: 256 target quads, one per thread ----
    {
        const float* p = tpts + ((long)b * N_ + s * CHUNK_ + threadIdx.x) * 3;
        float a0 = p[0], a1 = p[1], a2 = p[2];
        sq[threadIdx.x] = make_float4(-2.0f * a0, -2.0f * a1, -2.0f * a2,
                                      fmaf(a0, a0, fmaf(a1, a1, a2 * a2)));
    }
    __syncthreads();

    // ---- queries: 16 consecutive points = 192B -> 12 coalesced float4 loads ----
    const int iq0 = (blockIdx.x * blockDim.x + threadIdx.x) * Q_;
    const float4* qp4 = (const float4*)(qpts + ((long)b * N_ + iq0) * 3);
    float qx[Q_], qy[Q_], qz[Q_];
#pragma unroll
    for (int g = 0; g < Q_ / 4; ++g) {   // 4 queries per 3 float4s
        const float4 f0 = qp4[3 * g + 0];
        const float4 f1 = qp4[3 * g + 1];
        const float4 f2 = qp4[3 * g + 2];
        qx[4*g+0]=f0.x; qy[4*g+0]=f0.y; qz[4*g+0]=f0.z;
        qx[4*g+1]=f0.w; qy[4*g+1]=f1.x; qz[4*g+1]=f1.y;
        qx[4*g+2]=f1.z; qy[4*g+2]=f1.w; qz[4*g+2]=f2.x;
        qx[4*g+3]=f2.y; qy[4*g+3]=f2.z; qz[4*g+3]=f2.w;
    }

    float m[Q_];
#pragma unroll
    for (int i = 0; i < Q_; ++i) m[i] = __builtin_inff();

    // per query per 4 targets: 12 fma + 2 min3 = 14 ops / 4 pairs = 3.5/pair
#define COMPUTE(T)                                                                     \
    {                                                                                  \
        _Pragma("unroll")                                                              \
        for (int i = 0; i < Q_; ++i) {                                                 \
            float s0 = fmaf(qx[i], T[0].x, fmaf(qy[i], T[0].y, fmaf(qz[i], T[0].z, T[0].w))); \
            float s1 = fmaf(qx[i], T[1].x, fmaf(qy[i], T[1].y, fmaf(qz[i], T[1].z, T[1].w))); \
            float s2 = fmaf(qx[i], T[2].x, fmaf(qy[i], T[2].y, fmaf(qz[i], T[2].z, T[2].w))); \
            float s3 = fmaf(qx[i], T[3].x, fmaf(qy[i], T[3].y, fmaf(qz[i], T[3].z, T[3].w))); \
            float u0 = fminf(fminf(s0, s1), s2);        /* v_min3 */                   \
            m[i]     = fminf(fminf(s3, u0), m[i]);      /* v_min3 */                   \
        }                                                                              \
    }

    // ---- scan: 4-target ping-pong (DS waits are in-order countable) ----
    float4 ta[4], tb[4];
#pragma unroll
    for (int k = 0; k < 4; ++k) ta[k] = sq[k];

    for (int j = 0; j < CHUNK_; j += 8) {
#pragma unroll
        for (int k = 0; k < 4; ++k) tb[k] = sq[j + 4 + k];
        COMPUTE(ta)
        // last iteration prefetches sq[CHUNK_..CHUNK_+3] -> pad, never used
#pragma unroll
        for (int k = 0; k < 4; ++k) ta[k] = sq[j + 8 + k];
        COMPUTE(tb)
    }
#undef COMPUTE

    // ---- emit partial mins (four float4 stores, contiguous 64B/thread) ----
    float* dst = part + (long)s * (B_ * N_) + (long)b * N_ + iq0;
#pragma unroll
    for (int g = 0; g < Q_ / 4; ++g) {
        float r0, r1, r2, r3;
        {
            float xn;
            xn = fmaf(qx[4*g+0], qx[4*g+0], fmaf(qy[4*g+0], qy[4*g+0], qz[4*g+0] * qz[4*g+0]));
            r0 = fmaxf(m[4*g+0] + xn, 0.0f);
            xn = fmaf(qx[4*g+1], qx[4*g+1], fmaf(qy[4*g+1], qy[4*g+1], qz[4*g+1] * qz[4*g+1]));
            r1 = fmaxf(m[4*g+1] + xn, 0.0f);
            xn = fmaf(qx[4*g+2], qx[4*g+2], fmaf(qy[4*g+2], qy[4*g+2], qz[4*g+2] * qz[4*g+2]));
            r2 = fmaxf(m[4*g+2] + xn, 0.0f);
            xn = fmaf(qx[4*g+3], qx[4*g+3], fmaf(qy[4*g+3], qy[4*g+3], qz[4*g+3] * qz[4*g+3]));
            r3 = fmaxf(m[4*g+3] + xn, 0.0f);
        }
        *(float4*)(dst + 4 * g) = make_float4(r0, r1, r2, r3);
    }
}

// One thread per query slot: min over S_ partials, then deterministic block sum.
__global__ __launch_bounds__(256)
void merge_kernel(const float* __restrict__ partX, const float* __restrict__ partY,
                  float* __restrict__ bsum, int BN) {
    const int g = blockIdx.x * blockDim.x + threadIdx.x;
    const float* base = (g < BN) ? (partX + g) : (partY + (g - BN));

    float m = __builtin_inff();
#pragma unroll
    for (int s = 0; s < S_; ++s)
        m = fminf(m, base[(long)s * BN]);

    for (int off = 32; off > 0; off >>= 1)
        m += __shfl_down(m, off, 64);
    __shared__ float wsum[4];
    const int lane = threadIdx.x & 63;
    const int w    = threadIdx.x >> 6;
    if (lane == 0) wsum[w] = m;
    __syncthreads();
    if (threadIdx.x == 0)
        bsum[blockIdx.x] = (wsum[0] + wsum[1]) + (wsum[2] + wsum[3]);
}

// Single wave: deterministic sum of block partials, scaled.
__global__ __launch_bounds__(64)
void final_kernel(const float* __restrict__ bsum, float* __restrict__ out,
                  int nb, float scale) {
    float s = 0.0f;
    for (int k = threadIdx.x; k < nb; k += 64)
        s += bsum[k];
    for (int off = 32; off > 0; off >>= 1)
        s += __shfl_down(s, off, 64);
    if (threadIdx.x == 0) out[0] = s * scale;
}

extern "C" void kernel_launch(void* const* d_in, const int* in_sizes, int n_in,
                              void* d_out, int out_size, void* d_ws, size_t ws_size,
                              hipStream_t stream) {
    const float* x = (const float*)d_in[0];  // [8, 8192, 3]
    const float* y = (const float*)d_in[1];  // [8, 8192, 3]
    float* out = (float*)d_out;

    const int BN = B_ * N_;

    float* partX = (float*)d_ws;                 // S_*BN floats = 8.4 MB
    float* partY = partX + (size_t)S_ * BN;      // 8.4 MB
    float* bsum  = partY + (size_t)S_ * BN;

    // fused both-direction minpass: grid (2, 8, 64) = 1024 blocks = 4/CU
    minpass_kernel<<<dim3(N_ / (256 * Q_), B_, 2 * S_), 256, 0, stream>>>(
        x, y, partX, partY);

    const int nb = 2 * BN / 256;  // 512
    merge_kernel<<<nb, 256, 0, stream>>>(partX, partY, bsum, BN);
    final_kernel<<<1, 64, 0, stream>>>(bsum, out, nb, 1.0f / 65536.0f);
}

// Round 11
// 139.527 us; speedup vs baseline: 1.0253x; 1.0253x over previous
//
#include <hip/hip_runtime.h>
#include <math.h>
#include <stdint.h>

// Chamfer distance, B=8, N=M=8192, D=3, fp32.
// out = mean_m( min_n dist2 ) + mean_n( min_m dist2 )
//
// dist2 = |q|^2 + (|t|^2 - 2 q.t); block stages its chunk's target quads
// (-2t, |t|^2) into LDS; inner loop = uniform-address ds_read_b128 broadcast.
// R10: INLINE-ASM LOAD SCHEDULE. R5/R8/R9 post-mortems proved the compiler
// always collapses register tiles (VGPR 36/40/52 vs needed 64+) into
// read->wait->compute slices with ~1 target in flight -> ~120cyc LDS latency
// exposed per target -> stuck at 79-86us (60% VALU eff). Fix: ds_read_b128
// issued from volatile asm in ping-pong 2-target batches with manual
// s_waitcnt lgkmcnt(2) + sched_barrier(0) (guide rule #18). Loads are asm,
// math stays C. Q=16 -> LDS pipe 20.5us/CU (43%) under the 48us VALU floor.
// Geometry: S=32, grid (2,8,64)=1024 blocks = 4/CU exact, ~95 VGPR = 4 waves/SIMD.
// No atomics in minpass (R2 lesson); partial mins via coalesced stores.

#define B_      8
#define N_      8192
#define Q_      16           // queries per thread
#define S_      32           // target splits per pass
#define CHUNK_  (N_ / S_)    // 256 targets per block

typedef float f32x4 __attribute__((ext_vector_type(4)));

// Two ds_read_b128 from wave-uniform LDS address ADDR at byte offsets O0/O1.
// volatile asm: program order among asm blocks is preserved; outputs are the
// ONLY source of target values so the compiler cannot re-slice the batch.
#define ISSUE2(d0, d1, ADDR, O0, O1)                                   \
    asm volatile("ds_read_b128 %0, %2 offset:" O0 "\n\t"               \
                 "ds_read_b128 %1, %2 offset:" O1                      \
                 : "=&v"(d0), "=&v"(d1) : "v"(ADDR))

// Wait until <=2 ds_reads outstanding (the ping-pong partner batch stays in
// flight), then fence the scheduler so no dependent VALU hoists above the
// wait (rule #18: "memory" clobber does not order register-only FMAs).
#define WAIT2()                                                        \
    asm volatile("s_waitcnt lgkmcnt(2)" ::: "memory");                 \
    __builtin_amdgcn_sched_barrier(0)

__global__ __launch_bounds__(256)
void minpass_kernel(const float* __restrict__ x, const float* __restrict__ y,
                    float* __restrict__ partX, float* __restrict__ partY) {
    __shared__ float4 sq[CHUNK_ + 4];   // +4: ping-pong prefetch overshoot pad

    const int b    = blockIdx.y;
    const int z    = blockIdx.z;       // 0..63
    const int pass = z >> 5;           // 0: q=x,t=y   1: q=y,t=x
    const int s    = z & (S_ - 1);

    const float* qpts = pass ? y : x;
    const float* tpts = pass ? x : y;
    float*       part = pass ? partY : partX;

    // ---- stage: 256 target quads, one per thread ----
    {
        const float* p = tpts + ((long)b * N_ + s * CHUNK_ + threadIdx.x) * 3;
        float a0 = p[0], a1 = p[1], a2 = p[2];
        if (threadIdx.x < CHUNK_)
            sq[threadIdx.x] = make_float4(-2.0f * a0, -2.0f * a1, -2.0f * a2,
                                          fmaf(a0, a0, fmaf(a1, a1, a2 * a2)));
    }
    __syncthreads();

    // ---- queries: 16 consecutive points = 192B -> 12 coalesced float4 loads ----
    const int iq0 = (blockIdx.x * blockDim.x + threadIdx.x) * Q_;
    const float4* qp4 = (const float4*)(qpts + ((long)b * N_ + iq0) * 3);
    float qx[Q_], qy[Q_], qz[Q_];
#pragma unroll
    for (int g = 0; g < Q_ / 4; ++g) {   // 4 queries per 3 float4s
        const float4 f0 = qp4[3 * g + 0];
        const float4 f1 = qp4[3 * g + 1];
        const float4 f2 = qp4[3 * g + 2];
        qx[4*g+0]=f0.x; qy[4*g+0]=f0.y; qz[4*g+0]=f0.z;
        qx[4*g+1]=f0.w; qy[4*g+1]=f1.x; qz[4*g+1]=f1.y;
        qx[4*g+2]=f1.z; qy[4*g+2]=f1.w; qz[4*g+2]=f2.x;
        qx[4*g+3]=f2.y; qy[4*g+3]=f2.z; qz[4*g+3]=f2.w;
    }

    float m[Q_];
#pragma unroll
    for (int i = 0; i < Q_; ++i) m[i] = __builtin_inff();

    // per query per 2 targets: 6 fma + 1 min3 = 7 ops / 2 pairs = 3.5/pair
#define COMPUTE(T0, T1)                                                               \
    {                                                                                 \
        _Pragma("unroll")                                                             \
        for (int i = 0; i < Q_; ++i) {                                                \
            float s0 = fmaf(qx[i], T0.x, fmaf(qy[i], T0.y, fmaf(qz[i], T0.z, T0.w))); \
            float s1 = fmaf(qx[i], T1.x, fmaf(qy[i], T1.y, fmaf(qz[i], T1.z, T1.w))); \
            m[i] = fminf(fminf(s0, s1), m[i]);   /* v_min3 */                         \
        }                                                                             \
    }

    // ---- scan: asm ping-pong, 2 targets per batch, depth-1 prefetch ----
    // LDS byte address of sq[0] (addrspace(3) pointer == 32-bit LDS offset).
    uint32_t addr = (uint32_t)(uintptr_t)(&sq[0]);
    f32x4 a0, a1, b0, b1;
    ISSUE2(a0, a1, addr, "0", "16");     // targets 0,1
    ISSUE2(b0, b1, addr, "32", "48");    // targets 2,3

    for (int j = 0; j < CHUNK_; j += 4) {
        WAIT2();                         // batch A landed (B still in flight)
        COMPUTE(a0, a1);
        ISSUE2(a0, a1, addr, "64", "80");    // prefetch next A (j+4, j+5)
        WAIT2();                         // batch B landed (A' in flight)
        COMPUTE(b0, b1);
        ISSUE2(b0, b1, addr, "96", "112");   // prefetch next B (j+6, j+7)
        addr += 64;
        // last iteration prefetches sq[CHUNK_..CHUNK_+3] -> pad, never used
    }
    asm volatile("s_waitcnt lgkmcnt(0)" ::: "memory");  // drain dangling prefetch
#undef COMPUTE

    // ---- emit partial mins (four float4 stores, contiguous 64B/thread) ----
    float* dst = part + (long)s * (B_ * N_) + (long)b * N_ + iq0;
#pragma unroll
    for (int g = 0; g < Q_ / 4; ++g) {
        float r0, r1, r2, r3;
        {
            float xn;
            xn = fmaf(qx[4*g+0], qx[4*g+0], fmaf(qy[4*g+0], qy[4*g+0], qz[4*g+0] * qz[4*g+0]));
            r0 = fmaxf(m[4*g+0] + xn, 0.0f);
            xn = fmaf(qx[4*g+1], qx[4*g+1], fmaf(qy[4*g+1], qy[4*g+1], qz[4*g+1] * qz[4*g+1]));
            r1 = fmaxf(m[4*g+1] + xn, 0.0f);
            xn = fmaf(qx[4*g+2], qx[4*g+2], fmaf(qy[4*g+2], qy[4*g+2], qz[4*g+2] * qz[4*g+2]));
            r2 = fmaxf(m[4*g+2] + xn, 0.0f);
            xn = fmaf(qx[4*g+3], qx[4*g+3], fmaf(qy[4*g+3], qy[4*g+3], qz[4*g+3] * qz[4*g+3]));
            r3 = fmaxf(m[4*g+3] + xn, 0.0f);
        }
        *(float4*)(dst + 4 * g) = make_float4(r0, r1, r2, r3);
    }
}

// One thread per query slot: min over S_ partials, then deterministic block sum.
__global__ __launch_bounds__(256)
void merge_kernel(const float* __restrict__ partX, const float* __restrict__ partY,
                  float* __restrict__ bsum, int BN) {
    const int g = blockIdx.x * blockDim.x + threadIdx.x;
    const float* base = (g < BN) ? (partX + g) : (partY + (g - BN));

    float m = __builtin_inff();
#pragma unroll
    for (int s = 0; s < S_; ++s)
        m = fminf(m, base[(long)s * BN]);

    for (int off = 32; off > 0; off >>= 1)
        m += __shfl_down(m, off, 64);
    __shared__ float wsum[4];
    const int lane = threadIdx.x & 63;
    const int w    = threadIdx.x >> 6;
    if (lane == 0) wsum[w] = m;
    __syncthreads();
    if (threadIdx.x == 0)
        bsum[blockIdx.x] = (wsum[0] + wsum[1]) + (wsum[2] + wsum[3]);
}

// Single wave: deterministic sum of block partials, scaled.
__global__ __launch_bounds__(64)
void final_kernel(const float* __restrict__ bsum, float* __restrict__ out,
                  int nb, float scale) {
    float s = 0.0f;
    for (int k = threadIdx.x; k < nb; k += 64)
        s += bsum[k];
    for (int off = 32; off > 0; off >>= 1)
        s += __shfl_down(s, off, 64);
    if (threadIdx.x == 0) out[0] = s * scale;
}

extern "C" void kernel_launch(void* const* d_in, const int* in_sizes, int n_in,
                              void* d_out, int out_size, void* d_ws, size_t ws_size,
                              hipStream_t stream) {
    const float* x = (const float*)d_in[0];  // [8, 8192, 3]
    const float* y = (const float*)d_in[1];  // [8, 8192, 3]
    float* out = (float*)d_out;

    const int BN = B_ * N_;

    float* partX = (float*)d_ws;                 // S_*BN floats = 8.4 MB
    float* partY = partX + (size_t)S_ * BN;      // 8.4 MB
    float* bsum  = partY + (size_t)S_ * BN;

    // fused both-direction minpass: grid (2, 8, 64) = 1024 blocks = 4/CU
    minpass_kernel<<<dim3(N_ / (256 * Q_), B_, 2 * S_), 256, 0, stream>>>(
        x, y, partX, partY);

    const int nb = 2 * BN / 256;  // 512
    merge_kernel<<<nb, 256, 0, stream>>>(partX, partY, bsum, BN);
    final_kernel<<<1, 64, 0, stream>>>(bsum, out, nb, 1.0f / 65536.0f);
}